// Round 23
// baseline (114.997 us; speedup 1.0000x reference)
//
#include <hip/hip_runtime.h>
#include <math.h>

typedef unsigned int u32;
typedef unsigned long long u64;

constexpr int NB   = 32;     // batch
constexpr int NN   = 50000;  // boxes per image
constexpr int NC   = 10;     // classes
constexpr int KK   = 512;    // PRE_NMS_TOPK
constexpr int MAXD = 100;    // MAX_DETECTIONS
constexpr int CAP  = 2048;   // per-(b,c) candidate list capacity
constexpr int LCAP = 192;    // per-class per-block LDS staging (expect ~39)
constexpr int GCH  = 2500;   // rows per gather chunk (50000 = 20*2500)
constexpr int KMAX = 1024;   // compile-time sort bound (expect M ~781)
constexpr u32 TBIN = 252;    // digest-bin threshold: x >~ 0.984375 -> ~781/class
constexpr int RLIM = 192;    // eager mask rows (walk rarely passes ~150)

// output section offsets (floats)
constexpr int OFF_BOX = 0;
constexpr int OFF_SC  = NB * MAXD * 4;
constexpr int OFF_LB  = OFF_SC + NB * MAXD;
constexpr int OFF_RT  = OFF_LB + NB * MAXD;
constexpr int OFF_TR  = OFF_RT + NB * MAXD * 3;

__device__ __forceinline__ u32 ord_f32(float s) {
  u32 u = __float_as_uint(s);
  return (u & 0x80000000u) ? ~u : (u | 0x80000000u);
}
__device__ __forceinline__ float unord_f32(u32 o) {
  u32 u = (o & 0x80000000u) ? (o & 0x7FFFFFFFu) : ~o;
  return __uint_as_float(u);
}
// key: high 32 = ordered masked score, low 32 = ~idx (ties -> lower idx wins)
__device__ __forceinline__ u64 make_key(float s, u32 i) {
  float sp = (s > 0.01f) ? s : -INFINITY;
  return ((u64)ord_f32(sp) << 32) | (u64)(u32)(~i);
}
// linear-quantized monotone 16-bit digest (0 = invalid)
__device__ __forceinline__ u32 digest16(float x) {
  if (!(x > 0.01f)) return 0;
  u32 q = (u32)(x * 65536.0f);
  return q > 65535u ? 65535u : q;
}
// uniform-lane reads (lane index is wave-uniform)
__device__ __forceinline__ float readlane_f(float v, int lane) {
  return __int_as_float(__builtin_amdgcn_readlane(__float_as_int(v), lane));
}
__device__ __forceinline__ u64 readlane_u64(u64 v, int lane) {
  u32 lo = __builtin_amdgcn_readlane((u32)v, lane);
  u32 hi = __builtin_amdgcn_readlane((u32)(v >> 32), lane);
  return ((u64)hi << 32) | lo;
}
__device__ __forceinline__ int clamp_idx(int idx) {
  return idx < 0 ? 0 : (idx >= NN ? NN - 1 : idx);
}

// ---------- K1: single-pass gather, fixed threshold, LDS-staged ----------
__global__ __launch_bounds__(512) void gather_kernel(
    const float* __restrict__ cls, u64* __restrict__ glist,
    u32* __restrict__ gcnt) {
  const int blk = blockIdx.x;              // 640 = 32 images x 20 chunks
  const int b = blk / 20, ch = blk % 20;   // chunk = 2500 rows = 25000 floats
  const float* src = cls + (size_t)b * NN * NC + (size_t)ch * GCH * NC;
  __shared__ u32 lcnt[NC];
  __shared__ u32 lbase[NC];
  __shared__ u64 lbuf[NC][LCAP];           // 15 KiB staging
  const int t = threadIdx.x;
  if (t < NC) lcnt[t] = 0;
  __syncthreads();
  for (int q = t; q < GCH * NC / 4; q += 512) {
    float4 v = ((const float4*)src)[q];
    float arr[4] = {v.x, v.y, v.z, v.w};
#pragma unroll
    for (int k = 0; k < 4; ++k) {
      int e = q * 4 + k;
      int c = e % 10;
      float x = arr[k];
      if ((digest16(x) >> 8) >= TBIN) {
        u32 idx = (u32)((ch * (GCH * NC) + e) / 10);
        u32 p = atomicAdd(&lcnt[c], 1u);
        if (p < (u32)LCAP) {
          lbuf[c][p] = make_key(x, idx);
        } else {  // staging overflow fallback: direct global append
          u32 g = atomicAdd(&gcnt[b * NC + c], 1u);
          if (g < (u32)CAP) glist[(size_t)(b * NC + c) * CAP + g] = make_key(x, idx);
        }
      }
    }
  }
  __syncthreads();
  if (t < NC) {  // one ranged reservation per class per block
    u32 n = min(lcnt[t], (u32)LCAP);
    lbase[t] = atomicAdd(&gcnt[b * NC + t], n);
  }
  __syncthreads();
  for (int c = 0; c < NC; ++c) {  // coalesced flush
    u32 n = min(lcnt[c], (u32)LCAP);
    u32 base = lbase[c];
    for (u32 i = t; i < n; i += 512) {
      u32 p = base + i;
      if (p < (u32)CAP) glist[(size_t)(b * NC + c) * CAP + p] = lbuf[c][i];
    }
  }
}

// ---- K2: fused per-(b,c) rank-sort top-512 + parallel-mask NMS ----
// LDS (38.1 KiB): cand[0,8K) prank[8K,24K) sel[24K,28K) bx4[28K,36K)
// ars[36K,38K) kmask[38K,+64). Post-sort rowm[192][9] aliases [0,13.5K)
// (9-u64 = 72 B row stride -> conflict-light diagonal/batched reads).
__global__ __launch_bounds__(512) void selnms_kernel(
    const float* __restrict__ cls, const u64* __restrict__ glist,
    const u32* __restrict__ gcnt, const float* __restrict__ boxes,
    int* __restrict__ tidx, float* __restrict__ ksc) {
  __shared__ __align__(16) unsigned char smem[38976];
  u64* cand = (u64*)smem;                              // [0, 8K)
  ushort (*prank)[8] = (ushort(*)[8])(smem + 8192);    // [8K, 24K)
  u64* sel = (u64*)(smem + 24576);                     // [24K, 28K)
  float4* bx4 = (float4*)(smem + 28672);               // [28K, 36K)
  float* ars = (float*)(smem + 36864);                 // [36K, 38K)
  u64* kmask = (u64*)(smem + 38912);                   // 64 B
  u64 (*rowm)[9] = (u64(*)[9])smem;                    // [0, 13.5K) post-sort
  __shared__ int s_cnt, s_d;

  // XCD-aware swizzle (bijective: 320 = 8 * 40): each XCD gets 40
  // consecutive bc = 4 whole images -> boxes/cls locality in its L2.
  const int bc = (blockIdx.x & 7) * 40 + (blockIdx.x >> 3);
  const int b = bc / NC;
  const int t = threadIdx.x;                           // 512 thr = 8 waves
  const int lane = t & 63, wv = t >> 6;

  int M = (int)gcnt[bc];
  if (M >= KK && M <= KMAX) {
    // fast path: real keys then distinct tiny pads ((u64)i < any real key)
    for (int i = t; i < KMAX; i += 512)
      cand[i] = (i < M) ? glist[(size_t)bc * CAP + i] : (u64)i;
  } else {
    // rare path: exact re-selection via 12-bit digest histogram (in prank)
    const int c = bc % NC;
    const float* sbase = cls + (size_t)b * NN * NC + c;
    u32* hist = (u32*)prank;  // 4096 u32 = 16 KiB
    for (int i = t; i < 4096; i += 512) hist[i] = 0;
    if (t == 0) s_cnt = 0;
    __syncthreads();
    for (int i = t; i < NN; i += 512)
      atomicAdd(&hist[digest16(sbase[(size_t)i * NC]) >> 4], 1u);
    __syncthreads();
    if (t == 0) {
      u32 run = 0, d = 1;
      for (int i = 4095; i >= 1; --i) {
        run += hist[i];
        if (run >= (u32)KK) { d = (u32)i; break; }
        d = 1;
      }
      s_d = (int)d;
    }
    __syncthreads();
    const u32 dstar = (u32)s_d;
    for (int i = t; i < KMAX; i += 512) cand[i] = (u64)i;  // pads
    __syncthreads();
    for (int i = t; i < NN; i += 512) {
      float x = sbase[(size_t)i * NC];
      u32 dg = digest16(x) >> 4;
      if (dg >= dstar && dg >= 1) {
        int p = atomicAdd(&s_cnt, 1);
        if (p < KMAX) cand[p] = make_key(x, (u32)i);
      }
    }
    __syncthreads();
    M = min(s_cnt, KMAX);
  }

  // T14 async-stage: issue this thread's 2 candidate-box loads NOW; the
  // ~7us of phase-A compute hides their latency.
  const u64 c0 = cand[t];
  const u64 c1 = cand[t + 512];
  const int pidx0 = clamp_idx((int)(~(u32)c0));
  const int pidx1 = clamp_idx((int)(~(u32)c1));
  const float4 pb0 = *(const float4*)(boxes + ((size_t)b * NN + pidx0) * 4);
  const float4 pb1 = *(const float4*)(boxes + ((size_t)b * NN + pidx1) * 4);

  sel[t] = make_key(-INFINITY, 0);
  __syncthreads();

  // Sort Phase A: wave wv ranks ALL i against j-slice [wv*128, wv*128+128)
  {
    u64 myk[16];
#pragma unroll
    for (int k = 0; k < 16; ++k) myk[k] = cand[lane + k * 64];
    int rnk[16];
#pragma unroll
    for (int k = 0; k < 16; ++k) rnk[k] = 0;
    const int j0 = wv * 128;
    const int rem = M - j0;
    const int jjmax = rem <= 0 ? 0 : (rem >= 128 ? 64 : ((rem + 1) >> 1));
    for (int jj = 0; jj < jjmax; ++jj) {
      const ulonglong2 v = *(const ulonglong2*)&cand[j0 + jj * 2];
#pragma unroll
      for (int k = 0; k < 16; ++k) {
        rnk[k] += (v.x > myk[k]) ? 1 : 0;
        rnk[k] += (v.y > myk[k]) ? 1 : 0;
      }
    }
#pragma unroll
    for (int k = 0; k < 16; ++k) prank[lane + k * 64][wv] = (ushort)rnk[k];
  }
  __syncthreads();
  // Sort Phase B: sum 8 partials per i; scatter key AND preloaded box to rank
  {
    const uint4 pv0 = *(const uint4*)&prank[t][0];
    const int r0 = (int)(pv0.x & 0xFFFFu) + (int)(pv0.x >> 16) +
                   (int)(pv0.y & 0xFFFFu) + (int)(pv0.y >> 16) +
                   (int)(pv0.z & 0xFFFFu) + (int)(pv0.z >> 16) +
                   (int)(pv0.w & 0xFFFFu) + (int)(pv0.w >> 16);
    if (t < M && r0 < KK) {
      sel[r0] = c0;
      bx4[r0] = pb0;
      ars[r0] = (pb0.z - pb0.x) * (pb0.w - pb0.y);
    }
    const int i1 = t + 512;
    const uint4 pv1 = *(const uint4*)&prank[i1][0];
    const int r1 = (int)(pv1.x & 0xFFFFu) + (int)(pv1.x >> 16) +
                   (int)(pv1.y & 0xFFFFu) + (int)(pv1.y >> 16) +
                   (int)(pv1.z & 0xFFFFu) + (int)(pv1.z >> 16) +
                   (int)(pv1.w & 0xFFFFu) + (int)(pv1.w >> 16);
    if (i1 < M && r1 < KK) {
      sel[r1] = c1;
      bx4[r1] = pb1;
      ars[r1] = (pb1.z - pb1.x) * (pb1.w - pb1.y);
    }
  }
  __syncthreads();

  // indices out (coalesced); boxes already staged in LDS by phase B
  tidx[bc * KK + t] = clamp_idx((int)(~(u32)sel[t]));

  // each wave fills per-lane j-box registers from LDS (conflict-free b128)
  float jx1[8], jy1[8], jx2[8], jy2[8], jar[8];
#pragma unroll
  for (int q = 0; q < 8; ++q) {
    const float4 bb = bx4[q * 64 + lane];
    jx1[q] = bb.x; jy1[q] = bb.y; jx2[q] = bb.z; jy2[q] = bb.w;
    jar[q] = ars[q * 64 + lane];
  }
  __syncthreads();  // cand/prank now fully dead; rowm may be written

  // RN32(inter/uni) > 0.5  <=>  inter/uni > 0.5+2^-25
  //   <=>  (inter - 0.5f*uni) > uni*2^-25f   [all-f32 EXACT: 0.5*uni exact
  //   scale; inter-uni/2 exact by Sterbenz when inter >= uni/2 (inter <=
  //   uni always), sign preserved otherwise; uni*2^-25 exact scale]

  // eager mask build for rows [0,192) only (words g=0..2); walk rarely
  // passes ~150 candidates; rows >=192 are built on demand in the walk.
#pragma unroll
  for (int g = 0; g < RLIM / 64; ++g) {
    for (int rr = 0; rr < 8; ++rr) {
      const int il = wv + 8 * rr;          // wave-uniform lane of box i
      const int i = g * 64 + il;
      const float bix1 = readlane_f(jx1[g], il);
      const float biy1 = readlane_f(jy1[g], il);
      const float bix2 = readlane_f(jx2[g], il);
      const float biy2 = readlane_f(jy2[g], il);
      const float bia  = readlane_f(jar[g], il);
      u64 m[8];
#pragma unroll
      for (int q = 0; q < 8; ++q) {
        m[q] = 0;
        if (q >= g) {  // compile-time guard
          float ix1 = fmaxf(bix1, jx1[q]);
          float iy1 = fmaxf(biy1, jy1[q]);
          float ix2 = fminf(bix2, jx2[q]);
          float iy2 = fminf(biy2, jy2[q]);
          float iw = fmaxf(ix2 - ix1, 0.0f);
          float ih = fmaxf(iy2 - iy1, 0.0f);
          float inter = iw * ih;
          float uni = bia + jar[q] - inter;
          bool s = (uni > 0.0f) && ((inter - 0.5f * uni) > uni * 0x1p-25f);
          m[q] = __ballot(s);
        }
      }
      u64 word = m[0];
#pragma unroll
      for (int q = 1; q < 8; ++q) word = (lane == q) ? m[q] : word;
      if (lane < 8) rowm[i][lane] = word;
    }
  }
  __syncthreads();

  if (wv == 0) {
    // walk: in-word suppression from register-held diagonal blocks (no LDS
    // in the per-keep chain); cross-word rows batch-applied at word ends.
    u64 vw_[8], kw[8];
#pragma unroll
    for (int q = 0; q < 8; ++q) {
      const float sc = unord_f32((u32)(sel[q * 64 + lane] >> 32));
      vw_[q] = __ballot(sc > 0.01f);
      kw[q] = 0;
    }
    // diagonal blocks: lane l holds row (w*64+l) restricted to word w
    const u64 diag0 = rowm[0 * 64 + lane][0];
    const u64 diag1 = rowm[1 * 64 + lane][1];
    const u64 diag2 = rowm[2 * 64 + lane][2];
    u64 vsup = 0;  // lane q holds accumulated suppression word q (q < 8)
    int count = 0;
    bool done = false;
#pragma unroll
    for (int w = 0; w < 8; ++w) {  // w compile-time in each unrolled copy
      if (!done) {
        u64 avail = vw_[w] & ~readlane_u64(vsup, w);
        if (w < RLIM / 64) {
          const u64 dg = (w == 0) ? diag0 : (w == 1) ? diag1 : diag2;
          u64 kwm = 0;
          while (avail) {
            const int bbit = (int)__builtin_ctzll(avail);
            kwm |= 1ull << bbit;
            if (++count == MAXD) { done = true; break; }
            const u64 rowd = readlane_u64(dg, bbit);  // ~20 cyc, no LDS
            const u64 mask_gt = (bbit == 63) ? 0ull : (~0ull << (bbit + 1));
            avail &= ~rowd & mask_gt;
          }
          kw[w] = kwm;
          if (!done) {
            // batch-apply kept rows to future words (2-deep pipelined reads)
            u64 acc = 0, km = kwm;
            while (km) {
              const int b2 = (int)__builtin_ctzll(km);
              km &= km - 1;
              const u64 v1 = (lane < 8) ? rowm[w * 64 + b2][lane] : 0;
              if (km) {
                const int b3 = (int)__builtin_ctzll(km);
                km &= km - 1;
                const u64 v2 = (lane < 8) ? rowm[w * 64 + b3][lane] : 0;
                acc |= v2;
              }
              acc |= v1;
            }
            vsup |= acc;
          }
        } else {
          // on-demand row build (statistically never; exactness guard)
          while (avail) {
            const int bbit = (int)__builtin_ctzll(avail);
            kw[w] |= 1ull << bbit;
            if (++count == MAXD) { done = true; break; }
            const float bix1 = readlane_f(jx1[w], bbit);
            const float biy1 = readlane_f(jy1[w], bbit);
            const float bix2 = readlane_f(jx2[w], bbit);
            const float biy2 = readlane_f(jy2[w], bbit);
            const float bia  = readlane_f(jar[w], bbit);
            u64 m[8];
#pragma unroll
            for (int q = 0; q < 8; ++q) {
              m[q] = 0;
              if (q >= w) {  // compile-time guard (w static per copy)
                float ix1 = fmaxf(bix1, jx1[q]);
                float iy1 = fmaxf(biy1, jy1[q]);
                float ix2 = fminf(bix2, jx2[q]);
                float iy2 = fminf(biy2, jy2[q]);
                float iw = fmaxf(ix2 - ix1, 0.0f);
                float ih = fmaxf(iy2 - iy1, 0.0f);
                float inter = iw * ih;
                float uni = bia + jar[q] - inter;
                bool s = (uni > 0.0f) && ((inter - 0.5f * uni) > uni * 0x1p-25f);
                m[q] = __ballot(s);
              }
            }
            u64 word = m[0];
#pragma unroll
            for (int q = 1; q < 8; ++q) word = (lane == q) ? m[q] : word;
            vsup |= word;
            const u64 mask_gt = (bbit == 63) ? 0ull : (~0ull << (bbit + 1));
            avail = vw_[w] & ~readlane_u64(vsup, w) & mask_gt;
          }
        }
      }
    }
    if (lane < 8) {  // publish keep words (static selection, rule #20)
      u64 word = kw[0];
#pragma unroll
      for (int q = 1; q < 8; ++q) word = (lane == q) ? kw[q] : word;
      kmask[lane] = word;
    }
  }
  __syncthreads();
  {
    const float sc = unord_f32((u32)(sel[t] >> 32));
    const bool keep = (kmask[t >> 6] >> (t & 63)) & 1ull;
    ksc[(size_t)bc * KK + t] = keep ? sc : -INFINITY;
  }
}

// ---- K3: per-image top-100 (wave-partitioned rank-sort) + gather ----
__global__ __launch_bounds__(512) void final_kernel(
    const float* __restrict__ boxes, const float* __restrict__ rot,
    const float* __restrict__ trans, const int* __restrict__ tidx,
    const float* __restrict__ ksc, float* __restrict__ out) {
  const int b = blockIdx.x;
  __shared__ __align__(16) u64 ck[KMAX];
  __shared__ __align__(16) ushort prank[KMAX][8];
  __shared__ u64 top[MAXD];
  __shared__ int cnt;
  const int t = threadIdx.x;  // 512 threads = 8 waves
  const int lane = t & 63, wv = t >> 6;
  if (t == 0) cnt = 0;
  if (t < MAXD) top[t] = make_key(-INFINITY, 0);
  for (int i = t; i < KMAX; i += 512) ck[i] = (u64)i;  // distinct tiny pads
  __syncthreads();
  for (int j = t; j < NC * KK; j += 512) {
    float s = ksc[b * NC * KK + j];
    if (s != -INFINITY) {
      int p = atomicAdd(&cnt, 1);
      if (p < KMAX) ck[p] = ((u64)ord_f32(s) << 32) | (u64)(u32)(~(u32)j);
    }
  }
  __syncthreads();
  const int n = min(cnt, KMAX);  // <= 1000 by construction
  {
    u64 myk[16];
#pragma unroll
    for (int k = 0; k < 16; ++k) myk[k] = ck[lane + k * 64];
    int rnk[16];
#pragma unroll
    for (int k = 0; k < 16; ++k) rnk[k] = 0;
    const int j0 = wv * 128;
    const int rem = n - j0;
    const int jjmax = rem <= 0 ? 0 : (rem >= 128 ? 64 : ((rem + 1) >> 1));
    for (int jj = 0; jj < jjmax; ++jj) {
      const ulonglong2 v = *(const ulonglong2*)&ck[j0 + jj * 2];
#pragma unroll
      for (int k = 0; k < 16; ++k) {
        rnk[k] += (v.x > myk[k]) ? 1 : 0;
        rnk[k] += (v.y > myk[k]) ? 1 : 0;
      }
    }
#pragma unroll
    for (int k = 0; k < 16; ++k) prank[lane + k * 64][wv] = (ushort)rnk[k];
  }
  __syncthreads();
#pragma unroll
  for (int h = 0; h < 2; ++h) {
    const int i = h * 512 + t;
    const uint4 pv = *(const uint4*)&prank[i][0];
    const int r = (int)(pv.x & 0xFFFFu) + (int)(pv.x >> 16) +
                  (int)(pv.y & 0xFFFFu) + (int)(pv.y >> 16) +
                  (int)(pv.z & 0xFFFFu) + (int)(pv.z >> 16) +
                  (int)(pv.w & 0xFFFFu) + (int)(pv.w >> 16);
    if (i < n && r < MAXD) top[r] = ck[i];
  }
  __syncthreads();

  if (t < MAXD) {
    float b0 = -1.f, b1 = -1.f, b2 = -1.f, b3 = -1.f;
    float os = -1.f, ol = -1.f;
    float r0 = -1.f, r1 = -1.f, r2 = -1.f;
    float t0 = -1.f, t1 = -1.f, t2 = -1.f;
    const u64 k = top[t];
    const float sc = unord_f32((u32)(k >> 32));
    if (sc != -INFINITY) {  // valid (reference: isfinite)
      int j = (int)(~(u32)k);
      int c = j >> 9, slot = j & (KK - 1);
      int idx = tidx[(b * NC + c) * KK + slot];
      os = sc;
      ol = (float)c;
      const float4 bx = *(const float4*)(boxes + ((size_t)b * NN + idx) * 4);
      b0 = bx.x; b1 = bx.y; b2 = bx.z; b3 = bx.w;
      const float* rp = rot + ((size_t)b * NN + idx) * 3;
      r0 = rp[0]; r1 = rp[1]; r2 = rp[2];
      const float* tp = trans + ((size_t)b * NN + idx) * 3;
      t0 = tp[0]; t1 = tp[1]; t2 = tp[2];
    }
    const int o = b * MAXD + t;
    out[OFF_BOX + (size_t)o * 4 + 0] = b0;
    out[OFF_BOX + (size_t)o * 4 + 1] = b1;
    out[OFF_BOX + (size_t)o * 4 + 2] = b2;
    out[OFF_BOX + (size_t)o * 4 + 3] = b3;
    out[OFF_SC + o] = os;
    out[OFF_LB + o] = ol;
    out[OFF_RT + (size_t)o * 3 + 0] = r0;
    out[OFF_RT + (size_t)o * 3 + 1] = r1;
    out[OFF_RT + (size_t)o * 3 + 2] = r2;
    out[OFF_TR + (size_t)o * 3 + 0] = t0;
    out[OFF_TR + (size_t)o * 3 + 1] = t1;
    out[OFF_TR + (size_t)o * 3 + 2] = t2;
  }
}

extern "C" void kernel_launch(void* const* d_in, const int* in_sizes, int n_in,
                              void* d_out, int out_size, void* d_ws, size_t ws_size,
                              hipStream_t stream) {
  const float* boxes = (const float*)d_in[0];
  const float* cls   = (const float*)d_in[1];
  const float* rot   = (const float*)d_in[2];
  const float* trans = (const float*)d_in[3];
  float* out = (float*)d_out;

  u64* glist = (u64*)d_ws;                              // 5.24 MB
  int* tidx  = (int*)(glist + (size_t)NB * NC * CAP);   // 640 KB
  float* ksc = (float*)(tidx + NB * NC * KK);           // 640 KB
  u32* gcnt  = (u32*)(ksc + NB * NC * KK);              // 1.3 KB

  hipMemsetAsync(gcnt, 0, NB * NC * sizeof(u32), stream);
  gather_kernel<<<NB * 20, 512, 0, stream>>>(cls, glist, gcnt);
  selnms_kernel<<<NB * NC, 512, 0, stream>>>(cls, glist, gcnt, boxes, tidx, ksc);
  final_kernel<<<NB, 512, 0, stream>>>(boxes, rot, trans, tidx, ksc, out);
}

// Round 24
// 110.961 us; speedup vs baseline: 1.0364x; 1.0364x over previous
//
#include <hip/hip_runtime.h>
#include <math.h>

typedef unsigned int u32;
typedef unsigned long long u64;

constexpr int NB   = 32;     // batch
constexpr int NN   = 50000;  // boxes per image
constexpr int NC   = 10;     // classes
constexpr int KK   = 512;    // PRE_NMS_TOPK
constexpr int MAXD = 100;    // MAX_DETECTIONS
constexpr int CAP  = 2048;   // per-(b,c) candidate list capacity
constexpr int LCAP = 192;    // per-class per-block LDS staging (expect ~39)
constexpr int GCH  = 2500;   // rows per gather chunk (50000 = 20*2500)
constexpr int KMAX = 1024;   // compile-time sort bound (expect M ~781)
constexpr u32 TBIN = 252;    // digest-bin threshold: x >~ 0.984375 -> ~781/class
constexpr int RLIM = 192;    // eager mask rows (walk rarely passes ~150)

// output section offsets (floats)
constexpr int OFF_BOX = 0;
constexpr int OFF_SC  = NB * MAXD * 4;
constexpr int OFF_LB  = OFF_SC + NB * MAXD;
constexpr int OFF_RT  = OFF_LB + NB * MAXD;
constexpr int OFF_TR  = OFF_RT + NB * MAXD * 3;

__device__ __forceinline__ u32 ord_f32(float s) {
  u32 u = __float_as_uint(s);
  return (u & 0x80000000u) ? ~u : (u | 0x80000000u);
}
__device__ __forceinline__ float unord_f32(u32 o) {
  u32 u = (o & 0x80000000u) ? (o & 0x7FFFFFFFu) : ~o;
  return __uint_as_float(u);
}
// key: high 32 = ordered masked score, low 32 = ~idx (ties -> lower idx wins)
__device__ __forceinline__ u64 make_key(float s, u32 i) {
  float sp = (s > 0.01f) ? s : -INFINITY;
  return ((u64)ord_f32(sp) << 32) | (u64)(u32)(~i);
}
// linear-quantized monotone 16-bit digest (0 = invalid)
__device__ __forceinline__ u32 digest16(float x) {
  if (!(x > 0.01f)) return 0;
  u32 q = (u32)(x * 65536.0f);
  return q > 65535u ? 65535u : q;
}
// uniform-lane reads (lane index is wave-uniform)
__device__ __forceinline__ float readlane_f(float v, int lane) {
  return __int_as_float(__builtin_amdgcn_readlane(__float_as_int(v), lane));
}
__device__ __forceinline__ u64 readlane_u64(u64 v, int lane) {
  u32 lo = __builtin_amdgcn_readlane((u32)v, lane);
  u32 hi = __builtin_amdgcn_readlane((u32)(v >> 32), lane);
  return ((u64)hi << 32) | lo;
}
__device__ __forceinline__ int clamp_idx(int idx) {
  return idx < 0 ? 0 : (idx >= NN ? NN - 1 : idx);
}

// ---------- K1: single-pass gather, fixed threshold, LDS-staged ----------
__global__ __launch_bounds__(512) void gather_kernel(
    const float* __restrict__ cls, u64* __restrict__ glist,
    u32* __restrict__ gcnt) {
  const int blk = blockIdx.x;              // 640 = 32 images x 20 chunks
  const int b = blk / 20, ch = blk % 20;   // chunk = 2500 rows = 25000 floats
  const float* src = cls + (size_t)b * NN * NC + (size_t)ch * GCH * NC;
  __shared__ u32 lcnt[NC];
  __shared__ u32 lbase[NC];
  __shared__ u64 lbuf[NC][LCAP];           // 15 KiB staging
  const int t = threadIdx.x;
  if (t < NC) lcnt[t] = 0;
  __syncthreads();
  for (int q = t; q < GCH * NC / 4; q += 512) {
    float4 v = ((const float4*)src)[q];
    float arr[4] = {v.x, v.y, v.z, v.w};
#pragma unroll
    for (int k = 0; k < 4; ++k) {
      int e = q * 4 + k;
      int c = e % 10;
      float x = arr[k];
      if ((digest16(x) >> 8) >= TBIN) {
        u32 idx = (u32)((ch * (GCH * NC) + e) / 10);
        u32 p = atomicAdd(&lcnt[c], 1u);
        if (p < (u32)LCAP) {
          lbuf[c][p] = make_key(x, idx);
        } else {  // staging overflow fallback: direct global append
          u32 g = atomicAdd(&gcnt[b * NC + c], 1u);
          if (g < (u32)CAP) glist[(size_t)(b * NC + c) * CAP + g] = make_key(x, idx);
        }
      }
    }
  }
  __syncthreads();
  if (t < NC) {  // one ranged reservation per class per block
    u32 n = min(lcnt[t], (u32)LCAP);
    lbase[t] = atomicAdd(&gcnt[b * NC + t], n);
  }
  __syncthreads();
  for (int c = 0; c < NC; ++c) {  // coalesced flush
    u32 n = min(lcnt[c], (u32)LCAP);
    u32 base = lbase[c];
    for (u32 i = t; i < n; i += 512) {
      u32 p = base + i;
      if (p < (u32)CAP) glist[(size_t)(b * NC + c) * CAP + p] = lbuf[c][i];
    }
  }
}

// ---- K2a: half-problem rank-sort. 640 blocks = 2 per (b,c); each block
// ranks its 512-key half against ALL keys and scatters rank<512 keys+boxes
// (prefetched) to rank-ordered global selg/bxg -> K2b reads are coalesced.
__global__ __launch_bounds__(512) void sort_kernel(
    const float* __restrict__ cls, const u64* __restrict__ glist,
    const u32* __restrict__ gcnt, const float* __restrict__ boxes,
    u64* __restrict__ selg, float4* __restrict__ bxg) {
  __shared__ __align__(16) unsigned char smem[16448];
  u64* cand = (u64*)smem;                            // [0, 8K)
  ushort (*prank)[8] = (ushort(*)[8])(smem + 8192);  // [8K, 16K)
  __shared__ int s_cnt, s_d;
  const int p = blockIdx.x >> 1, half = blockIdx.x & 1;
  // XCD-aware swizzle (bijective: 320 = 8*40): pair p -> bc
  const int bc = (p & 7) * 40 + (p >> 3);
  const int b = bc / NC;
  const int t = threadIdx.x, lane = t & 63, wv = t >> 6;

  int M = (int)gcnt[bc];
  const bool fast = (M >= KK && M <= KMAX);
  if (fast) {
    // real keys then distinct tiny pads ((u64)i < any real key: bit63 set)
    for (int i = t; i < KMAX; i += 512)
      cand[i] = (i < M) ? glist[(size_t)bc * CAP + i] : (u64)i;
  } else {
    // rare path: exact re-selection via 12-bit digest histogram.
    // hist aliases the whole 16K smem; cand written only after dstar found.
    const int c = bc % NC;
    const float* sbase = cls + (size_t)b * NN * NC + c;
    u32* hist = (u32*)smem;  // 4096 u32 = 16 KiB
    for (int i = t; i < 4096; i += 512) hist[i] = 0;
    if (t == 0) s_cnt = 0;
    __syncthreads();
    for (int i = t; i < NN; i += 512)
      atomicAdd(&hist[digest16(sbase[(size_t)i * NC]) >> 4], 1u);
    __syncthreads();
    if (t == 0) {
      u32 run = 0, d = 1;
      for (int i = 4095; i >= 1; --i) {
        run += hist[i];
        if (run >= (u32)KK) { d = (u32)i; break; }
        d = 1;
      }
      s_d = (int)d;
    }
    __syncthreads();
    const u32 dstar = (u32)s_d;
    for (int i = t; i < KMAX; i += 512) cand[i] = (u64)i;  // pads (hist dead)
    __syncthreads();
    for (int i = t; i < NN; i += 512) {
      float x = sbase[(size_t)i * NC];
      u32 dg = digest16(x) >> 4;
      if (dg >= dstar && dg >= 1) {
        int pq = atomicAdd(&s_cnt, 1);
        if (pq < KMAX) cand[pq] = make_key(x, (u32)i);
      }
    }
    __syncthreads();
    M = min(s_cnt, KMAX);
  }

  // T14: prefetch my half's box NOW (own cand writes in fast path; rare
  // path fetches at scatter). Latency hides under phase A.
  u64 ck0 = 0;
  float4 pb0;
  if (fast) {
    ck0 = cand[half * 512 + t];  // own write (fill stride 512)
    const int pidx = clamp_idx((int)(~(u32)ck0));
    pb0 = *(const float4*)(boxes + ((size_t)b * NN + pidx) * 4);
  }
  __syncthreads();

  const int h2lo = fast ? half : 0;
  const int h2hi = fast ? half : 1;
  for (int h2 = h2lo; h2 <= h2hi; ++h2) {
    // Phase A: wave wv ranks this half's 512 keys vs j-slice [wv*128, +128)
    {
      u64 myk[8];
#pragma unroll
      for (int k = 0; k < 8; ++k) myk[k] = cand[h2 * 512 + lane + k * 64];
      int rnk[8];
#pragma unroll
      for (int k = 0; k < 8; ++k) rnk[k] = 0;
      const int j0 = wv * 128;
      const int rem = M - j0;
      const int jjmax = rem <= 0 ? 0 : (rem >= 128 ? 64 : ((rem + 1) >> 1));
      for (int jj = 0; jj < jjmax; ++jj) {
        const ulonglong2 v = *(const ulonglong2*)&cand[j0 + jj * 2];
#pragma unroll
        for (int k = 0; k < 8; ++k) {
          rnk[k] += (v.x > myk[k]) ? 1 : 0;
          rnk[k] += (v.y > myk[k]) ? 1 : 0;
        }
      }
#pragma unroll
      for (int k = 0; k < 8; ++k) prank[lane + k * 64][wv] = (ushort)rnk[k];
    }
    __syncthreads();
    // Phase B: thread t owns iloc=t; scatter key + box to global rank slot
    {
      const uint4 pv = *(const uint4*)&prank[t][0];
      const int r = (int)(pv.x & 0xFFFFu) + (int)(pv.x >> 16) +
                    (int)(pv.y & 0xFFFFu) + (int)(pv.y >> 16) +
                    (int)(pv.z & 0xFFFFu) + (int)(pv.z >> 16) +
                    (int)(pv.w & 0xFFFFu) + (int)(pv.w >> 16);
      const int ig = h2 * 512 + t;
      if (ig < M && r < KK) {
        const u64 key = fast ? ck0 : cand[ig];
        selg[(size_t)bc * KK + r] = key;
        if (fast) {
          bxg[(size_t)bc * KK + r] = pb0;
        } else {
          const int pidx = clamp_idx((int)(~(u32)key));
          bxg[(size_t)bc * KK + r] =
              *(const float4*)(boxes + ((size_t)b * NN + pidx) * 4);
        }
      }
    }
    if (h2 < h2hi) __syncthreads();  // rare path: prank reused
  }
  // NOTE: fewer than 512 real candidates can't happen (dstar/TBIN ensure
  // M >= KK whenever >=512 valid scores exist; with this data always true).
  // If M < KK, unwritten selg slots would be stale -- guarded below.
  if (M < KK) {  // defensive: fill ranks [M, KK) with -inf keys
    for (int r = M + t; r < KK; r += 512) {
      selg[(size_t)bc * KK + r] = make_key(-INFINITY, 0);
      bxg[(size_t)bc * KK + r] =
          *(const float4*)(boxes + ((size_t)b * NN + 0) * 4);
    }
  }
}

// ---- K2b: NMS. All inputs coalesced (selg, bxg). Build rowm + walk. ----
__global__ __launch_bounds__(512) void nms_kernel(
    const u64* __restrict__ selg, const float4* __restrict__ bxg,
    int* __restrict__ tidx, float* __restrict__ ksc) {
  __shared__ __align__(16) unsigned char smem[26560];
  float4* bx4 = (float4*)smem;                       // [0, 8K)
  float* ars = (float*)(smem + 8192);                // [8K, 10K)
  float* sscore = (float*)(smem + 10240);            // [10K, 12K)
  u64 (*rowm)[9] = (u64(*)[9])(smem + 12288);        // [12K, 26.1K)
  u64* kmask = (u64*)(smem + 26432);                 // 64 B
  const int bc = (blockIdx.x & 7) * 40 + (blockIdx.x >> 3);
  const int t = threadIdx.x, lane = t & 63, wv = t >> 6;

  {
    const u64 k = selg[(size_t)bc * KK + t];         // coalesced
    tidx[bc * KK + t] = clamp_idx((int)(~(u32)k));
    const float4 bx = bxg[(size_t)bc * KK + t];      // coalesced
    bx4[t] = bx;
    ars[t] = (bx.z - bx.x) * (bx.w - bx.y);
    sscore[t] = unord_f32((u32)(k >> 32));
  }
  __syncthreads();

  // each wave fills per-lane j-box registers from LDS (conflict-free b128)
  float jx1[8], jy1[8], jx2[8], jy2[8], jar[8];
#pragma unroll
  for (int q = 0; q < 8; ++q) {
    const float4 bb = bx4[q * 64 + lane];
    jx1[q] = bb.x; jy1[q] = bb.y; jx2[q] = bb.z; jy2[q] = bb.w;
    jar[q] = ars[q * 64 + lane];
  }

  // RN32(inter/uni) > 0.5  <=>  inter/uni > 0.5+2^-25
  //   <=>  (inter - 0.5f*uni) > uni*2^-25f   [all-f32 EXACT: 0.5*uni exact
  //   scale; inter-uni/2 exact by Sterbenz when inter >= uni/2 (inter <=
  //   uni always), sign preserved otherwise; uni*2^-25 exact scale]

  // eager mask build for rows [0,192) (words g=0..2); rows >=192 on demand
#pragma unroll
  for (int g = 0; g < RLIM / 64; ++g) {
    for (int rr = 0; rr < 8; ++rr) {
      const int il = wv + 8 * rr;          // wave-uniform lane of box i
      const int i = g * 64 + il;
      const float bix1 = readlane_f(jx1[g], il);
      const float biy1 = readlane_f(jy1[g], il);
      const float bix2 = readlane_f(jx2[g], il);
      const float biy2 = readlane_f(jy2[g], il);
      const float bia  = readlane_f(jar[g], il);
      u64 m[8];
#pragma unroll
      for (int q = 0; q < 8; ++q) {
        m[q] = 0;
        if (q >= g) {  // compile-time guard
          float ix1 = fmaxf(bix1, jx1[q]);
          float iy1 = fmaxf(biy1, jy1[q]);
          float ix2 = fminf(bix2, jx2[q]);
          float iy2 = fminf(biy2, jy2[q]);
          float iw = fmaxf(ix2 - ix1, 0.0f);
          float ih = fmaxf(iy2 - iy1, 0.0f);
          float inter = iw * ih;
          float uni = bia + jar[q] - inter;
          bool s = (uni > 0.0f) && ((inter - 0.5f * uni) > uni * 0x1p-25f);
          m[q] = __ballot(s);
        }
      }
      u64 word = m[0];
#pragma unroll
      for (int q = 1; q < 8; ++q) word = (lane == q) ? m[q] : word;
      if (lane < 8) rowm[i][lane] = word;
    }
  }
  __syncthreads();

  if (wv == 0) {  // walk: rows <192 from rowm; >=192 built on demand
    u64 vw_[8], kw[8];
#pragma unroll
    for (int q = 0; q < 8; ++q) {
      const float sc = sscore[q * 64 + lane];
      vw_[q] = __ballot(sc > 0.01f);
      kw[q] = 0;
    }
    u64 vsup = 0;  // lane q holds accumulated suppression word q (q < 8)
    int count = 0;
    bool done = false;
#pragma unroll
    for (int w = 0; w < 8; ++w) {  // w compile-time in each unrolled copy
      if (!done) {
        u64 av = vw_[w] & ~readlane_u64(vsup, w);
        while (av) {
          const int bbit = (int)__builtin_ctzll(av);
          const int i = w * 64 + bbit;
          kw[w] |= 1ull << bbit;
          if (++count == MAXD) { done = true; break; }
          if (w < RLIM / 64) {
            const u64 row = (lane < 8) ? rowm[i][lane] : 0;
            vsup |= row;
          } else {
            // on-demand row build (statistically never; exactness guard)
            const float bix1 = readlane_f(jx1[w], bbit);
            const float biy1 = readlane_f(jy1[w], bbit);
            const float bix2 = readlane_f(jx2[w], bbit);
            const float biy2 = readlane_f(jy2[w], bbit);
            const float bia  = readlane_f(jar[w], bbit);
            u64 m[8];
#pragma unroll
            for (int q = 0; q < 8; ++q) {
              m[q] = 0;
              if (q >= w) {  // compile-time guard (w static per copy)
                float ix1 = fmaxf(bix1, jx1[q]);
                float iy1 = fmaxf(biy1, jy1[q]);
                float ix2 = fminf(bix2, jx2[q]);
                float iy2 = fminf(biy2, jy2[q]);
                float iw = fmaxf(ix2 - ix1, 0.0f);
                float ih = fmaxf(iy2 - iy1, 0.0f);
                float inter = iw * ih;
                float uni = bia + jar[q] - inter;
                bool s = (uni > 0.0f) && ((inter - 0.5f * uni) > uni * 0x1p-25f);
                m[q] = __ballot(s);
              }
            }
            u64 word = m[0];
#pragma unroll
            for (int q = 1; q < 8; ++q) word = (lane == q) ? m[q] : word;
            vsup |= word;
          }
          const u64 mask_gt = (bbit == 63) ? 0ull : (~0ull << (bbit + 1));
          av = vw_[w] & ~readlane_u64(vsup, w) & mask_gt;
        }
      }
    }
    if (lane < 8) {  // publish keep words (static selection, rule #20)
      u64 word = kw[0];
#pragma unroll
      for (int q = 1; q < 8; ++q) word = (lane == q) ? kw[q] : word;
      kmask[lane] = word;
    }
  }
  __syncthreads();
  {
    const float sc = sscore[t];
    const bool keep = (kmask[t >> 6] >> (t & 63)) & 1ull;
    ksc[(size_t)bc * KK + t] = keep ? sc : -INFINITY;
  }
}

// ---- K3: per-image top-100 (wave-partitioned rank-sort) + gather ----
__global__ __launch_bounds__(512) void final_kernel(
    const float* __restrict__ boxes, const float* __restrict__ rot,
    const float* __restrict__ trans, const int* __restrict__ tidx,
    const float* __restrict__ ksc, float* __restrict__ out) {
  const int b = blockIdx.x;
  __shared__ __align__(16) u64 ck[KMAX];
  __shared__ __align__(16) ushort prank[KMAX][8];
  __shared__ u64 top[MAXD];
  __shared__ int cnt;
  const int t = threadIdx.x;  // 512 threads = 8 waves
  const int lane = t & 63, wv = t >> 6;
  if (t == 0) cnt = 0;
  if (t < MAXD) top[t] = make_key(-INFINITY, 0);
  for (int i = t; i < KMAX; i += 512) ck[i] = (u64)i;  // distinct tiny pads
  __syncthreads();
  for (int j = t; j < NC * KK; j += 512) {
    float s = ksc[b * NC * KK + j];
    if (s != -INFINITY) {
      int p = atomicAdd(&cnt, 1);
      if (p < KMAX) ck[p] = ((u64)ord_f32(s) << 32) | (u64)(u32)(~(u32)j);
    }
  }
  __syncthreads();
  const int n = min(cnt, KMAX);  // <= 1000 by construction
  {
    u64 myk[16];
#pragma unroll
    for (int k = 0; k < 16; ++k) myk[k] = ck[lane + k * 64];
    int rnk[16];
#pragma unroll
    for (int k = 0; k < 16; ++k) rnk[k] = 0;
    const int j0 = wv * 128;
    const int rem = n - j0;
    const int jjmax = rem <= 0 ? 0 : (rem >= 128 ? 64 : ((rem + 1) >> 1));
    for (int jj = 0; jj < jjmax; ++jj) {
      const ulonglong2 v = *(const ulonglong2*)&ck[j0 + jj * 2];
#pragma unroll
      for (int k = 0; k < 16; ++k) {
        rnk[k] += (v.x > myk[k]) ? 1 : 0;
        rnk[k] += (v.y > myk[k]) ? 1 : 0;
      }
    }
#pragma unroll
    for (int k = 0; k < 16; ++k) prank[lane + k * 64][wv] = (ushort)rnk[k];
  }
  __syncthreads();
#pragma unroll
  for (int h = 0; h < 2; ++h) {
    const int i = h * 512 + t;
    const uint4 pv = *(const uint4*)&prank[i][0];
    const int r = (int)(pv.x & 0xFFFFu) + (int)(pv.x >> 16) +
                  (int)(pv.y & 0xFFFFu) + (int)(pv.y >> 16) +
                  (int)(pv.z & 0xFFFFu) + (int)(pv.z >> 16) +
                  (int)(pv.w & 0xFFFFu) + (int)(pv.w >> 16);
    if (i < n && r < MAXD) top[r] = ck[i];
  }
  __syncthreads();

  if (t < MAXD) {
    float b0 = -1.f, b1 = -1.f, b2 = -1.f, b3 = -1.f;
    float os = -1.f, ol = -1.f;
    float r0 = -1.f, r1 = -1.f, r2 = -1.f;
    float t0 = -1.f, t1 = -1.f, t2 = -1.f;
    const u64 k = top[t];
    const float sc = unord_f32((u32)(k >> 32));
    if (sc != -INFINITY) {  // valid (reference: isfinite)
      int j = (int)(~(u32)k);
      int c = j >> 9, slot = j & (KK - 1);
      int idx = tidx[(b * NC + c) * KK + slot];
      os = sc;
      ol = (float)c;
      const float4 bx = *(const float4*)(boxes + ((size_t)b * NN + idx) * 4);
      b0 = bx.x; b1 = bx.y; b2 = bx.z; b3 = bx.w;
      const float* rp = rot + ((size_t)b * NN + idx) * 3;
      r0 = rp[0]; r1 = rp[1]; r2 = rp[2];
      const float* tp = trans + ((size_t)b * NN + idx) * 3;
      t0 = tp[0]; t1 = tp[1]; t2 = tp[2];
    }
    const int o = b * MAXD + t;
    out[OFF_BOX + (size_t)o * 4 + 0] = b0;
    out[OFF_BOX + (size_t)o * 4 + 1] = b1;
    out[OFF_BOX + (size_t)o * 4 + 2] = b2;
    out[OFF_BOX + (size_t)o * 4 + 3] = b3;
    out[OFF_SC + o] = os;
    out[OFF_LB + o] = ol;
    out[OFF_RT + (size_t)o * 3 + 0] = r0;
    out[OFF_RT + (size_t)o * 3 + 1] = r1;
    out[OFF_RT + (size_t)o * 3 + 2] = r2;
    out[OFF_TR + (size_t)o * 3 + 0] = t0;
    out[OFF_TR + (size_t)o * 3 + 1] = t1;
    out[OFF_TR + (size_t)o * 3 + 2] = t2;
  }
}

extern "C" void kernel_launch(void* const* d_in, const int* in_sizes, int n_in,
                              void* d_out, int out_size, void* d_ws, size_t ws_size,
                              hipStream_t stream) {
  const float* boxes = (const float*)d_in[0];
  const float* cls   = (const float*)d_in[1];
  const float* rot   = (const float*)d_in[2];
  const float* trans = (const float*)d_in[3];
  float* out = (float*)d_out;

  u64* glist   = (u64*)d_ws;                             // 5.24 MB
  u64* selg    = glist + (size_t)NB * NC * CAP;          // 1.31 MB
  float4* bxg  = (float4*)(selg + (size_t)NB * NC * KK); // 2.62 MB
  int* tidx    = (int*)(bxg + (size_t)NB * NC * KK);     // 640 KB
  float* ksc   = (float*)(tidx + NB * NC * KK);          // 640 KB
  u32* gcnt    = (u32*)(ksc + NB * NC * KK);             // 1.3 KB

  hipMemsetAsync(gcnt, 0, NB * NC * sizeof(u32), stream);
  gather_kernel<<<NB * 20, 512, 0, stream>>>(cls, glist, gcnt);
  sort_kernel<<<NB * NC * 2, 512, 0, stream>>>(cls, glist, gcnt, boxes, selg, bxg);
  nms_kernel<<<NB * NC, 512, 0, stream>>>(selg, bxg, tidx, ksc);
  final_kernel<<<NB, 512, 0, stream>>>(boxes, rot, trans, tidx, ksc, out);
}

// Round 25
// 110.176 us; speedup vs baseline: 1.0438x; 1.0071x over previous
//
#include <hip/hip_runtime.h>
#include <math.h>

typedef unsigned int u32;
typedef unsigned long long u64;

constexpr int NB   = 32;     // batch
constexpr int NN   = 50000;  // boxes per image
constexpr int NC   = 10;     // classes
constexpr int KK   = 512;    // PRE_NMS_TOPK
constexpr int MAXD = 100;    // MAX_DETECTIONS
constexpr int CAP  = 2048;   // per-(b,c) candidate list capacity
constexpr int LCAP = 192;    // per-class per-block LDS staging (expect ~39)
constexpr int GCH  = 2500;   // rows per gather chunk (50000 = 20*2500)
constexpr int KMAX = 1024;   // compile-time sort bound (expect M ~781)
constexpr u32 TBIN = 252;    // digest-bin threshold: x >~ 0.984375 -> ~781/class
constexpr int RLIM = 192;    // eager mask rows (walk rarely passes ~150)

// output section offsets (floats)
constexpr int OFF_BOX = 0;
constexpr int OFF_SC  = NB * MAXD * 4;
constexpr int OFF_LB  = OFF_SC + NB * MAXD;
constexpr int OFF_RT  = OFF_LB + NB * MAXD;
constexpr int OFF_TR  = OFF_RT + NB * MAXD * 3;

__device__ __forceinline__ u32 ord_f32(float s) {
  u32 u = __float_as_uint(s);
  return (u & 0x80000000u) ? ~u : (u | 0x80000000u);
}
__device__ __forceinline__ float unord_f32(u32 o) {
  u32 u = (o & 0x80000000u) ? (o & 0x7FFFFFFFu) : ~o;
  return __uint_as_float(u);
}
// key: high 32 = ordered masked score, low 32 = ~idx (ties -> lower idx wins)
__device__ __forceinline__ u64 make_key(float s, u32 i) {
  float sp = (s > 0.01f) ? s : -INFINITY;
  return ((u64)ord_f32(sp) << 32) | (u64)(u32)(~i);
}
// linear-quantized monotone 16-bit digest (0 = invalid)
__device__ __forceinline__ u32 digest16(float x) {
  if (!(x > 0.01f)) return 0;
  u32 q = (u32)(x * 65536.0f);
  return q > 65535u ? 65535u : q;
}
// uniform-lane reads (lane index is wave-uniform)
__device__ __forceinline__ float readlane_f(float v, int lane) {
  return __int_as_float(__builtin_amdgcn_readlane(__float_as_int(v), lane));
}
__device__ __forceinline__ u64 readlane_u64(u64 v, int lane) {
  u32 lo = __builtin_amdgcn_readlane((u32)v, lane);
  u32 hi = __builtin_amdgcn_readlane((u32)(v >> 32), lane);
  return ((u64)hi << 32) | lo;
}
__device__ __forceinline__ int clamp_idx(int idx) {
  return idx < 0 ? 0 : (idx >= NN ? NN - 1 : idx);
}

// ---------- K0: zero gcnt (replaces 40us fillBufferAligned memset) ----------
__global__ __launch_bounds__(320) void init_kernel(u32* __restrict__ gcnt) {
  gcnt[threadIdx.x] = 0;  // 320 threads, 1 block, ~3us
}

// ---------- K1: single-pass gather, fixed threshold, LDS-staged ----------
__global__ __launch_bounds__(512) void gather_kernel(
    const float* __restrict__ cls, u64* __restrict__ glist,
    u32* __restrict__ gcnt) {
  const int blk = blockIdx.x;              // 640 = 32 images x 20 chunks
  const int b = blk / 20, ch = blk % 20;   // chunk = 2500 rows = 25000 floats
  const float* src = cls + (size_t)b * NN * NC + (size_t)ch * GCH * NC;
  __shared__ u32 lcnt[NC];
  __shared__ u32 lbase[NC];
  __shared__ u64 lbuf[NC][LCAP];           // 15 KiB staging
  const int t = threadIdx.x;
  if (t < NC) lcnt[t] = 0;
  __syncthreads();
  for (int q = t; q < GCH * NC / 4; q += 512) {
    float4 v = ((const float4*)src)[q];
    float arr[4] = {v.x, v.y, v.z, v.w};
#pragma unroll
    for (int k = 0; k < 4; ++k) {
      int e = q * 4 + k;
      int c = e % 10;
      float x = arr[k];
      if ((digest16(x) >> 8) >= TBIN) {
        u32 idx = (u32)((ch * (GCH * NC) + e) / 10);
        u32 p = atomicAdd(&lcnt[c], 1u);
        if (p < (u32)LCAP) {
          lbuf[c][p] = make_key(x, idx);
        } else {  // staging overflow fallback: direct global append
          u32 g = atomicAdd(&gcnt[b * NC + c], 1u);
          if (g < (u32)CAP) glist[(size_t)(b * NC + c) * CAP + g] = make_key(x, idx);
        }
      }
    }
  }
  __syncthreads();
  if (t < NC) {  // one ranged reservation per class per block
    u32 n = min(lcnt[t], (u32)LCAP);
    lbase[t] = atomicAdd(&gcnt[b * NC + t], n);
  }
  __syncthreads();
  for (int c = 0; c < NC; ++c) {  // coalesced flush
    u32 n = min(lcnt[c], (u32)LCAP);
    u32 base = lbase[c];
    for (u32 i = t; i < n; i += 512) {
      u32 p = base + i;
      if (p < (u32)CAP) glist[(size_t)(b * NC + c) * CAP + p] = lbuf[c][i];
    }
  }
}

// ---- K2a: half-problem rank-sort. 640 blocks = 2 per (b,c); each block
// ranks its 512-key half against ALL keys and scatters rank<512 keys+boxes
// (prefetched) to rank-ordered global selg/bxg -> K2b reads are coalesced.
__global__ __launch_bounds__(512) void sort_kernel(
    const float* __restrict__ cls, const u64* __restrict__ glist,
    const u32* __restrict__ gcnt, const float* __restrict__ boxes,
    u64* __restrict__ selg, float4* __restrict__ bxg) {
  __shared__ __align__(16) unsigned char smem[16448];
  u64* cand = (u64*)smem;                            // [0, 8K)
  ushort (*prank)[8] = (ushort(*)[8])(smem + 8192);  // [8K, 16K)
  __shared__ int s_cnt, s_d;
  const int p = blockIdx.x >> 1, half = blockIdx.x & 1;
  // XCD-aware swizzle (bijective: 320 = 8*40): pair p -> bc
  const int bc = (p & 7) * 40 + (p >> 3);
  const int b = bc / NC;
  const int t = threadIdx.x, lane = t & 63, wv = t >> 6;

  int M = (int)gcnt[bc];
  const bool fast = (M >= KK && M <= KMAX);
  if (fast) {
    // real keys then distinct tiny pads ((u64)i < any real key: bit63 set)
    for (int i = t; i < KMAX; i += 512)
      cand[i] = (i < M) ? glist[(size_t)bc * CAP + i] : (u64)i;
  } else {
    // rare path: exact re-selection via 12-bit digest histogram.
    // hist aliases the whole 16K smem; cand written only after dstar found.
    const int c = bc % NC;
    const float* sbase = cls + (size_t)b * NN * NC + c;
    u32* hist = (u32*)smem;  // 4096 u32 = 16 KiB
    for (int i = t; i < 4096; i += 512) hist[i] = 0;
    if (t == 0) s_cnt = 0;
    __syncthreads();
    for (int i = t; i < NN; i += 512)
      atomicAdd(&hist[digest16(sbase[(size_t)i * NC]) >> 4], 1u);
    __syncthreads();
    if (t == 0) {
      u32 run = 0, d = 1;
      for (int i = 4095; i >= 1; --i) {
        run += hist[i];
        if (run >= (u32)KK) { d = (u32)i; break; }
        d = 1;
      }
      s_d = (int)d;
    }
    __syncthreads();
    const u32 dstar = (u32)s_d;
    for (int i = t; i < KMAX; i += 512) cand[i] = (u64)i;  // pads (hist dead)
    __syncthreads();
    for (int i = t; i < NN; i += 512) {
      float x = sbase[(size_t)i * NC];
      u32 dg = digest16(x) >> 4;
      if (dg >= dstar && dg >= 1) {
        int pq = atomicAdd(&s_cnt, 1);
        if (pq < KMAX) cand[pq] = make_key(x, (u32)i);
      }
    }
    __syncthreads();
    M = min(s_cnt, KMAX);
  }

  // T14: prefetch my half's box NOW (own cand writes in fast path; rare
  // path fetches at scatter). Latency hides under phase A.
  u64 ck0 = 0;
  float4 pb0;
  if (fast) {
    ck0 = cand[half * 512 + t];  // own write (fill stride 512)
    const int pidx = clamp_idx((int)(~(u32)ck0));
    pb0 = *(const float4*)(boxes + ((size_t)b * NN + pidx) * 4);
  }
  __syncthreads();

  const int h2lo = fast ? half : 0;
  const int h2hi = fast ? half : 1;
  for (int h2 = h2lo; h2 <= h2hi; ++h2) {
    // Phase A: wave wv ranks this half's 512 keys vs j-slice [wv*128, +128)
    {
      u64 myk[8];
#pragma unroll
      for (int k = 0; k < 8; ++k) myk[k] = cand[h2 * 512 + lane + k * 64];
      int rnk[8];
#pragma unroll
      for (int k = 0; k < 8; ++k) rnk[k] = 0;
      const int j0 = wv * 128;
      const int rem = M - j0;
      const int jjmax = rem <= 0 ? 0 : (rem >= 128 ? 64 : ((rem + 1) >> 1));
      for (int jj = 0; jj < jjmax; ++jj) {
        const ulonglong2 v = *(const ulonglong2*)&cand[j0 + jj * 2];
#pragma unroll
        for (int k = 0; k < 8; ++k) {
          rnk[k] += (v.x > myk[k]) ? 1 : 0;
          rnk[k] += (v.y > myk[k]) ? 1 : 0;
        }
      }
#pragma unroll
      for (int k = 0; k < 8; ++k) prank[lane + k * 64][wv] = (ushort)rnk[k];
    }
    __syncthreads();
    // Phase B: thread t owns iloc=t; scatter key + box to global rank slot
    {
      const uint4 pv = *(const uint4*)&prank[t][0];
      const int r = (int)(pv.x & 0xFFFFu) + (int)(pv.x >> 16) +
                    (int)(pv.y & 0xFFFFu) + (int)(pv.y >> 16) +
                    (int)(pv.z & 0xFFFFu) + (int)(pv.z >> 16) +
                    (int)(pv.w & 0xFFFFu) + (int)(pv.w >> 16);
      const int ig = h2 * 512 + t;
      if (ig < M && r < KK) {
        const u64 key = fast ? ck0 : cand[ig];
        selg[(size_t)bc * KK + r] = key;
        if (fast) {
          bxg[(size_t)bc * KK + r] = pb0;
        } else {
          const int pidx = clamp_idx((int)(~(u32)key));
          bxg[(size_t)bc * KK + r] =
              *(const float4*)(boxes + ((size_t)b * NN + pidx) * 4);
        }
      }
    }
    if (h2 < h2hi) __syncthreads();  // rare path: prank reused
  }
  if (M < KK) {  // defensive: fill ranks [M, KK) with -inf keys
    for (int r = M + t; r < KK; r += 512) {
      selg[(size_t)bc * KK + r] = make_key(-INFINITY, 0);
      bxg[(size_t)bc * KK + r] =
          *(const float4*)(boxes + ((size_t)b * NN + 0) * 4);
    }
  }
}

// ---- K2b: NMS. All inputs coalesced (selg, bxg). Build rowm + walk. ----
__global__ __launch_bounds__(512) void nms_kernel(
    const u64* __restrict__ selg, const float4* __restrict__ bxg,
    int* __restrict__ tidx, float* __restrict__ ksc) {
  __shared__ __align__(16) unsigned char smem[26560];
  float4* bx4 = (float4*)smem;                       // [0, 8K)
  float* ars = (float*)(smem + 8192);                // [8K, 10K)
  float* sscore = (float*)(smem + 10240);            // [10K, 12K)
  u64 (*rowm)[9] = (u64(*)[9])(smem + 12288);        // [12K, 26.1K)
  u64* kmask = (u64*)(smem + 26432);                 // 64 B
  const int bc = (blockIdx.x & 7) * 40 + (blockIdx.x >> 3);
  const int t = threadIdx.x, lane = t & 63, wv = t >> 6;

  {
    const u64 k = selg[(size_t)bc * KK + t];         // coalesced
    tidx[bc * KK + t] = clamp_idx((int)(~(u32)k));
    const float4 bx = bxg[(size_t)bc * KK + t];      // coalesced
    bx4[t] = bx;
    ars[t] = (bx.z - bx.x) * (bx.w - bx.y);
    sscore[t] = unord_f32((u32)(k >> 32));
  }
  __syncthreads();

  // each wave fills per-lane j-box registers from LDS (conflict-free b128)
  float jx1[8], jy1[8], jx2[8], jy2[8], jar[8];
#pragma unroll
  for (int q = 0; q < 8; ++q) {
    const float4 bb = bx4[q * 64 + lane];
    jx1[q] = bb.x; jy1[q] = bb.y; jx2[q] = bb.z; jy2[q] = bb.w;
    jar[q] = ars[q * 64 + lane];
  }

  // RN32(inter/uni) > 0.5  <=>  inter/uni > 0.5+2^-25
  //   <=>  (inter - 0.5f*uni) > uni*2^-25f   [all-f32 EXACT: 0.5*uni exact
  //   scale; inter-uni/2 exact by Sterbenz when inter >= uni/2 (inter <=
  //   uni always), sign preserved otherwise; uni*2^-25 exact scale]

  // eager mask build for rows [0,192) (words g=0..2); rows >=192 on demand
#pragma unroll
  for (int g = 0; g < RLIM / 64; ++g) {
    for (int rr = 0; rr < 8; ++rr) {
      const int il = wv + 8 * rr;          // wave-uniform lane of box i
      const int i = g * 64 + il;
      const float bix1 = readlane_f(jx1[g], il);
      const float biy1 = readlane_f(jy1[g], il);
      const float bix2 = readlane_f(jx2[g], il);
      const float biy2 = readlane_f(jy2[g], il);
      const float bia  = readlane_f(jar[g], il);
      u64 m[8];
#pragma unroll
      for (int q = 0; q < 8; ++q) {
        m[q] = 0;
        if (q >= g) {  // compile-time guard
          float ix1 = fmaxf(bix1, jx1[q]);
          float iy1 = fmaxf(biy1, jy1[q]);
          float ix2 = fminf(bix2, jx2[q]);
          float iy2 = fminf(biy2, jy2[q]);
          float iw = fmaxf(ix2 - ix1, 0.0f);
          float ih = fmaxf(iy2 - iy1, 0.0f);
          float inter = iw * ih;
          float uni = bia + jar[q] - inter;
          bool s = (uni > 0.0f) && ((inter - 0.5f * uni) > uni * 0x1p-25f);
          m[q] = __ballot(s);
        }
      }
      u64 word = m[0];
#pragma unroll
      for (int q = 1; q < 8; ++q) word = (lane == q) ? m[q] : word;
      if (lane < 8) rowm[i][lane] = word;
    }
  }
  __syncthreads();

  if (wv == 0) {  // walk: rows <192 from rowm; >=192 built on demand
    u64 vw_[8], kw[8];
#pragma unroll
    for (int q = 0; q < 8; ++q) {
      const float sc = sscore[q * 64 + lane];
      vw_[q] = __ballot(sc > 0.01f);
      kw[q] = 0;
    }
    u64 vsup = 0;  // lane q holds accumulated suppression word q (q < 8)
    int count = 0;
    bool done = false;
#pragma unroll
    for (int w = 0; w < 8; ++w) {  // w compile-time in each unrolled copy
      if (!done) {
        u64 av = vw_[w] & ~readlane_u64(vsup, w);
        while (av) {
          const int bbit = (int)__builtin_ctzll(av);
          const int i = w * 64 + bbit;
          kw[w] |= 1ull << bbit;
          if (++count == MAXD) { done = true; break; }
          if (w < RLIM / 64) {
            const u64 row = (lane < 8) ? rowm[i][lane] : 0;
            vsup |= row;
          } else {
            // on-demand row build (statistically never; exactness guard)
            const float bix1 = readlane_f(jx1[w], bbit);
            const float biy1 = readlane_f(jy1[w], bbit);
            const float bix2 = readlane_f(jx2[w], bbit);
            const float biy2 = readlane_f(jy2[w], bbit);
            const float bia  = readlane_f(jar[w], bbit);
            u64 m[8];
#pragma unroll
            for (int q = 0; q < 8; ++q) {
              m[q] = 0;
              if (q >= w) {  // compile-time guard (w static per copy)
                float ix1 = fmaxf(bix1, jx1[q]);
                float iy1 = fmaxf(biy1, jy1[q]);
                float ix2 = fminf(bix2, jx2[q]);
                float iy2 = fminf(biy2, jy2[q]);
                float iw = fmaxf(ix2 - ix1, 0.0f);
                float ih = fmaxf(iy2 - iy1, 0.0f);
                float inter = iw * ih;
                float uni = bia + jar[q] - inter;
                bool s = (uni > 0.0f) && ((inter - 0.5f * uni) > uni * 0x1p-25f);
                m[q] = __ballot(s);
              }
            }
            u64 word = m[0];
#pragma unroll
            for (int q = 1; q < 8; ++q) word = (lane == q) ? m[q] : word;
            vsup |= word;
          }
          const u64 mask_gt = (bbit == 63) ? 0ull : (~0ull << (bbit + 1));
          av = vw_[w] & ~readlane_u64(vsup, w) & mask_gt;
        }
      }
    }
    if (lane < 8) {  // publish keep words (static selection, rule #20)
      u64 word = kw[0];
#pragma unroll
      for (int q = 1; q < 8; ++q) word = (lane == q) ? kw[q] : word;
      kmask[lane] = word;
    }
  }
  __syncthreads();
  {
    const float sc = sscore[t];
    const bool keep = (kmask[t >> 6] >> (t & 63)) & 1ull;
    ksc[(size_t)bc * KK + t] = keep ? sc : -INFINITY;
  }
}

// ---- K3: per-image top-100 (wave-partitioned rank-sort) + gather ----
__global__ __launch_bounds__(512) void final_kernel(
    const float* __restrict__ boxes, const float* __restrict__ rot,
    const float* __restrict__ trans, const int* __restrict__ tidx,
    const float* __restrict__ ksc, float* __restrict__ out) {
  const int b = blockIdx.x;
  __shared__ __align__(16) u64 ck[KMAX];
  __shared__ __align__(16) ushort prank[KMAX][8];
  __shared__ u64 top[MAXD];
  __shared__ int cnt;
  const int t = threadIdx.x;  // 512 threads = 8 waves
  const int lane = t & 63, wv = t >> 6;
  if (t == 0) cnt = 0;
  if (t < MAXD) top[t] = make_key(-INFINITY, 0);
  for (int i = t; i < KMAX; i += 512) ck[i] = (u64)i;  // distinct tiny pads
  __syncthreads();
  for (int j = t; j < NC * KK; j += 512) {
    float s = ksc[b * NC * KK + j];
    if (s != -INFINITY) {
      int p = atomicAdd(&cnt, 1);
      if (p < KMAX) ck[p] = ((u64)ord_f32(s) << 32) | (u64)(u32)(~(u32)j);
    }
  }
  __syncthreads();
  const int n = min(cnt, KMAX);  // <= 1000 by construction
  {
    u64 myk[16];
#pragma unroll
    for (int k = 0; k < 16; ++k) myk[k] = ck[lane + k * 64];
    int rnk[16];
#pragma unroll
    for (int k = 0; k < 16; ++k) rnk[k] = 0;
    const int j0 = wv * 128;
    const int rem = n - j0;
    const int jjmax = rem <= 0 ? 0 : (rem >= 128 ? 64 : ((rem + 1) >> 1));
    for (int jj = 0; jj < jjmax; ++jj) {
      const ulonglong2 v = *(const ulonglong2*)&ck[j0 + jj * 2];
#pragma unroll
      for (int k = 0; k < 16; ++k) {
        rnk[k] += (v.x > myk[k]) ? 1 : 0;
        rnk[k] += (v.y > myk[k]) ? 1 : 0;
      }
    }
#pragma unroll
    for (int k = 0; k < 16; ++k) prank[lane + k * 64][wv] = (ushort)rnk[k];
  }
  __syncthreads();
#pragma unroll
  for (int h = 0; h < 2; ++h) {
    const int i = h * 512 + t;
    const uint4 pv = *(const uint4*)&prank[i][0];
    const int r = (int)(pv.x & 0xFFFFu) + (int)(pv.x >> 16) +
                  (int)(pv.y & 0xFFFFu) + (int)(pv.y >> 16) +
                  (int)(pv.z & 0xFFFFu) + (int)(pv.z >> 16) +
                  (int)(pv.w & 0xFFFFu) + (int)(pv.w >> 16);
    if (i < n && r < MAXD) top[r] = ck[i];
  }
  __syncthreads();

  if (t < MAXD) {
    float b0 = -1.f, b1 = -1.f, b2 = -1.f, b3 = -1.f;
    float os = -1.f, ol = -1.f;
    float r0 = -1.f, r1 = -1.f, r2 = -1.f;
    float t0 = -1.f, t1 = -1.f, t2 = -1.f;
    const u64 k = top[t];
    const float sc = unord_f32((u32)(k >> 32));
    if (sc != -INFINITY) {  // valid (reference: isfinite)
      int j = (int)(~(u32)k);
      int c = j >> 9, slot = j & (KK - 1);
      int idx = tidx[(b * NC + c) * KK + slot];
      os = sc;
      ol = (float)c;
      const float4 bx = *(const float4*)(boxes + ((size_t)b * NN + idx) * 4);
      b0 = bx.x; b1 = bx.y; b2 = bx.z; b3 = bx.w;
      const float* rp = rot + ((size_t)b * NN + idx) * 3;
      r0 = rp[0]; r1 = rp[1]; r2 = rp[2];
      const float* tp = trans + ((size_t)b * NN + idx) * 3;
      t0 = tp[0]; t1 = tp[1]; t2 = tp[2];
    }
    const int o = b * MAXD + t;
    out[OFF_BOX + (size_t)o * 4 + 0] = b0;
    out[OFF_BOX + (size_t)o * 4 + 1] = b1;
    out[OFF_BOX + (size_t)o * 4 + 2] = b2;
    out[OFF_BOX + (size_t)o * 4 + 3] = b3;
    out[OFF_SC + o] = os;
    out[OFF_LB + o] = ol;
    out[OFF_RT + (size_t)o * 3 + 0] = r0;
    out[OFF_RT + (size_t)o * 3 + 1] = r1;
    out[OFF_RT + (size_t)o * 3 + 2] = r2;
    out[OFF_TR + (size_t)o * 3 + 0] = t0;
    out[OFF_TR + (size_t)o * 3 + 1] = t1;
    out[OFF_TR + (size_t)o * 3 + 2] = t2;
  }
}

extern "C" void kernel_launch(void* const* d_in, const int* in_sizes, int n_in,
                              void* d_out, int out_size, void* d_ws, size_t ws_size,
                              hipStream_t stream) {
  const float* boxes = (const float*)d_in[0];
  const float* cls   = (const float*)d_in[1];
  const float* rot   = (const float*)d_in[2];
  const float* trans = (const float*)d_in[3];
  float* out = (float*)d_out;

  u64* glist   = (u64*)d_ws;                             // 5.24 MB
  u64* selg    = glist + (size_t)NB * NC * CAP;          // 1.31 MB
  float4* bxg  = (float4*)(selg + (size_t)NB * NC * KK); // 2.62 MB
  int* tidx    = (int*)(bxg + (size_t)NB * NC * KK);     // 640 KB
  float* ksc   = (float*)(tidx + NB * NC * KK);          // 640 KB
  u32* gcnt    = (u32*)(ksc + NB * NC * KK);             // 1.3 KB

  init_kernel<<<1, 320, 0, stream>>>(gcnt);
  gather_kernel<<<NB * 20, 512, 0, stream>>>(cls, glist, gcnt);
  sort_kernel<<<NB * NC * 2, 512, 0, stream>>>(cls, glist, gcnt, boxes, selg, bxg);
  nms_kernel<<<NB * NC, 512, 0, stream>>>(selg, bxg, tidx, ksc);
  final_kernel<<<NB, 512, 0, stream>>>(boxes, rot, trans, tidx, ksc, out);
}